// Round 2
// baseline (579.667 us; speedup 1.0000x reference)
//
#include <hip/hip_runtime.h>
#include <hip/hip_bf16.h>
#include <type_traits>

// Decoder_bipartite: out[e] = sigmoid( relu( [z_src[row[e]] ; z_dst[col[e]]] @ W1^T + b1 ) @ W2^T + b2 )
// H=128, K=2H=256, E=1e6. bf16 MFMA (16x16x32), fp32 accum.
// R2: pre-convert z to bf16 in d_ws (halves gather traffic), 512-thr blocks (2 blk/CU -> 16 waves/CU).

#define H 128
#define K2 256
#define NW 8        // waves per block
#define BM (NW*32)  // edges per block-tile = 256

typedef __bf16 bf16x8 __attribute__((ext_vector_type(8)));
typedef float  f32x4  __attribute__((ext_vector_type(4)));

__device__ __forceinline__ bf16x8 cvt8(const float4 a, const float4 b) {
    bf16x8 r;
    r[0] = (__bf16)a.x; r[1] = (__bf16)a.y; r[2] = (__bf16)a.z; r[3] = (__bf16)a.w;
    r[4] = (__bf16)b.x; r[5] = (__bf16)b.y; r[6] = (__bf16)b.z; r[7] = (__bf16)b.w;
    return r;
}

// f32 -> bf16 conversion of z_src ++ z_dst into workspace (contiguous).
__global__ __launch_bounds__(256)
void prep_kernel(const float* __restrict__ zsrc, const float* __restrict__ zdst,
                 __bf16* __restrict__ zb, int nsrc_elems, int nchunks) {
    int c = blockIdx.x * blockDim.x + threadIdx.x;
    if (c >= nchunks) return;
    int base = c * 8;
    const float* src = (base < nsrc_elems) ? (zsrc + base) : (zdst + (base - nsrc_elems));
    const float4* p = reinterpret_cast<const float4*>(src);
    *reinterpret_cast<bf16x8*>(zb + base) = cvt8(p[0], p[1]);
}

template<bool ZBF16>
__global__ __launch_bounds__(512, 4)
void decoder_kernel(const void* __restrict__ zsrc_, const void* __restrict__ zdst_,
                    const int* __restrict__ row, const int* __restrict__ col,
                    const float* __restrict__ W1, const float* __restrict__ b1,
                    const float* __restrict__ W2, const float* __restrict__ b2,
                    float* __restrict__ out, int E, int ntiles) {
    using ZT = typename std::conditional<ZBF16, __bf16, float>::type;
    const ZT* zsrc = (const ZT*)zsrc_;
    const ZT* zdst = (const ZT*)zdst_;

    // W1^T packed in MFMA B-fragment order: slot = kb*8+nt, then lane, then 8 k-elems.
    __shared__ __bf16 sB[64 * 64 * 8];   // 64 KB

    const int tid  = threadIdx.x;
    const int lane = tid & 63;
    const int wave = tid >> 6;           // 0..7

    // ---- stage W1^T -> LDS (fragment-packed; conflict-free b128 reads later) ----
    #pragma unroll
    for (int i = 0; i < 8; ++i) {
        int c    = tid + 512 * i;          // chunk 0..4095
        int cl   = c & 63;
        int slot = c >> 6;
        int kb   = slot >> 3, nt = slot & 7;
        int n    = nt * 16 + (cl & 15);
        int k0   = kb * 32 + ((cl >> 4) << 3);
        const float4* wp = reinterpret_cast<const float4*>(W1 + n * K2 + k0);
        float4 w0 = wp[0], w1 = wp[1];
        *reinterpret_cast<bf16x8*>(&sB[(size_t)c * 8]) = cvt8(w0, w1);
    }
    // per-lane epilogue constants: b1 / W2 slices for col = lane&15 of each n-tile
    float b1v[8], w2v[8];
    #pragma unroll
    for (int nt = 0; nt < 8; ++nt) {
        b1v[nt] = b1[nt * 16 + (lane & 15)];
        w2v[nt] = W2[nt * 16 + (lane & 15)];
    }
    const float bias2 = b2[0];
    __syncthreads();   // sB ready; no LDS writes after this -> no barriers in loop

    const int koff = (lane >> 4) << 3;     // 0,8,16,24: this lane's k-offset in a 32-k block

    for (int tile = blockIdx.x; tile < ntiles; tile += gridDim.x) {
        const int rbase = tile * BM + wave * 32;
        int e0 = rbase + (lane & 15);
        int e1 = e0 + 16;
        int e0c = e0 < E ? e0 : E - 1;
        int e1c = e1 < E ? e1 : E - 1;
        const ZT* a0s = zsrc + (size_t)row[e0c] * H;
        const ZT* a1s = zsrc + (size_t)row[e1c] * H;
        const ZT* a0d = zdst + (size_t)col[e0c] * H;
        const ZT* a1d = zdst + (size_t)col[e1c] * H;

        f32x4 zero = {0.f, 0.f, 0.f, 0.f};
        f32x4 acc[2][8];
        #pragma unroll
        for (int mt = 0; mt < 2; ++mt)
            #pragma unroll
            for (int nt = 0; nt < 8; ++nt)
                acc[mt][nt] = zero;

        #pragma unroll
        for (int kb = 0; kb < 8; ++kb) {
            const ZT* p0 = (kb < 4) ? a0s : a0d;
            const ZT* p1 = (kb < 4) ? a1s : a1d;
            const int ko = (kb & 3) * 32 + koff;
            bf16x8 afr0, afr1;
            if constexpr (ZBF16) {
                afr0 = *reinterpret_cast<const bf16x8*>(p0 + ko);
                afr1 = *reinterpret_cast<const bf16x8*>(p1 + ko);
            } else {
                const float4* q0 = reinterpret_cast<const float4*>(p0 + ko);
                const float4* q1 = reinterpret_cast<const float4*>(p1 + ko);
                afr0 = cvt8(q0[0], q0[1]);
                afr1 = cvt8(q1[0], q1[1]);
            }
            #pragma unroll
            for (int nt = 0; nt < 8; ++nt) {
                bf16x8 bfr = *reinterpret_cast<const bf16x8*>(&sB[(size_t)((kb * 8 + nt) * 64 + lane) * 8]);
                acc[0][nt] = __builtin_amdgcn_mfma_f32_16x16x32_bf16(afr0, bfr, acc[0][nt], 0, 0, 0);
                acc[1][nt] = __builtin_amdgcn_mfma_f32_16x16x32_bf16(afr1, bfr, acc[1][nt], 0, 0, 0);
            }
        }

        // epilogue: +b1, ReLU, dot W2 across n (in-wave), +b2, sigmoid, store
        #pragma unroll
        for (int mt = 0; mt < 2; ++mt) {
            #pragma unroll
            for (int r = 0; r < 4; ++r) {
                float p = 0.f;
                #pragma unroll
                for (int nt = 0; nt < 8; ++nt) {
                    float h = acc[mt][nt][r] + b1v[nt];
                    h = h > 0.f ? h : 0.f;
                    p += h * w2v[nt];
                }
                p += __shfl_xor(p, 1);
                p += __shfl_xor(p, 2);
                p += __shfl_xor(p, 4);
                p += __shfl_xor(p, 8);
                int e = rbase + mt * 16 + ((lane >> 4) << 2) + r;
                if ((lane & 15) == 0 && e < E) {
                    float logit = p + bias2;
                    out[e] = 1.f / (1.f + __expf(-logit));
                }
            }
        }
    }
}

extern "C" void kernel_launch(void* const* d_in, const int* in_sizes, int n_in,
                              void* d_out, int out_size, void* d_ws, size_t ws_size,
                              hipStream_t stream) {
    const float* zsrc = (const float*)d_in[0];
    const float* zdst = (const float*)d_in[1];
    const int*   eli  = (const int*)d_in[2];   // [2,E] flat: row then col
    const float* W1   = (const float*)d_in[3];
    const float* b1   = (const float*)d_in[4];
    const float* W2   = (const float*)d_in[5];
    const float* b2   = (const float*)d_in[6];
    float* out = (float*)d_out;

    const int E = in_sizes[2] / 2;
    const int ntiles = (E + BM - 1) / BM;
    const int grid = ntiles < 1024 ? ntiles : 1024;

    const int nz = in_sizes[0] + in_sizes[1];
    const size_t need = (size_t)nz * sizeof(__bf16);
    if (ws_size >= need) {
        __bf16* zb = (__bf16*)d_ws;
        const int nchunks = nz / 8;
        prep_kernel<<<(nchunks + 255) / 256, 256, 0, stream>>>(zsrc, zdst, zb, in_sizes[0], nchunks);
        decoder_kernel<true><<<grid, 512, 0, stream>>>(zb, zb + in_sizes[0], eli, eli + E,
                                                       W1, b1, W2, b2, out, E, ntiles);
    } else {
        decoder_kernel<false><<<grid, 512, 0, stream>>>(zsrc, zdst, eli, eli + E,
                                                        W1, b1, W2, b2, out, E, ntiles);
    }
}

// Round 3
// 298.192 us; speedup vs baseline: 1.9439x; 1.9439x over previous
//
#include <hip/hip_runtime.h>
#include <hip/hip_bf16.h>
#include <type_traits>

// Decoder_bipartite: out[e] = sigmoid( relu( [z_src[row[e]] ; z_dst[col[e]]] @ W1^T + b1 ) @ W2^T + b2 )
// H=128, K=2H=256, E=1e6. bf16 MFMA (16x16x32), fp32 accum.
// R3: 256-thr blocks, launch_bounds(256,2) (no spills); bf16 z in d_ws; 32B/lane gathers
//     (128-B aligned segments) with matching k-permuted W1 fragment packing in LDS.

#define H 128
#define K2 256
#define NW 4
#define BM (NW * 32)   // 128 edges per block-tile

typedef __bf16 bf16x8  __attribute__((ext_vector_type(8)));
typedef __bf16 bf16x16 __attribute__((ext_vector_type(16)));
typedef float  f32x4   __attribute__((ext_vector_type(4)));

__device__ __forceinline__ bf16x8 cvt8(const float4 a, const float4 b) {
    bf16x8 r;
    r[0] = (__bf16)a.x; r[1] = (__bf16)a.y; r[2] = (__bf16)a.z; r[3] = (__bf16)a.w;
    r[4] = (__bf16)b.x; r[5] = (__bf16)b.y; r[6] = (__bf16)b.z; r[7] = (__bf16)b.w;
    return r;
}
__device__ __forceinline__ bf16x8 lo8(const bf16x16 v) {
    bf16x8 r;
    #pragma unroll
    for (int i = 0; i < 8; ++i) r[i] = v[i];
    return r;
}
__device__ __forceinline__ bf16x8 hi8(const bf16x16 v) {
    bf16x8 r;
    #pragma unroll
    for (int i = 0; i < 8; ++i) r[i] = v[i + 8];
    return r;
}

// f32 -> bf16 conversion of z_src ++ z_dst into workspace (contiguous).
__global__ __launch_bounds__(256)
void prep_kernel(const float* __restrict__ zsrc, const float* __restrict__ zdst,
                 __bf16* __restrict__ zb, int nsrc_elems, int nchunks) {
    int c = blockIdx.x * blockDim.x + threadIdx.x;
    if (c >= nchunks) return;
    int base = c * 8;
    const float* src = (base < nsrc_elems) ? (zsrc + base) : (zdst + (base - nsrc_elems));
    const float4* p = reinterpret_cast<const float4*>(src);
    *reinterpret_cast<bf16x8*>(zb + base) = cvt8(p[0], p[1]);
}

template<bool ZBF16>
__global__ __launch_bounds__(256, 2)
void decoder_kernel(const void* __restrict__ zsrc_, const void* __restrict__ zdst_,
                    const int* __restrict__ row, const int* __restrict__ col,
                    const float* __restrict__ W1, const float* __restrict__ b1,
                    const float* __restrict__ W2, const float* __restrict__ b2,
                    float* __restrict__ out, int E, int ntiles) {
    using ZT = typename std::conditional<ZBF16, __bf16, float>::type;
    const ZT* zsrc = (const ZT*)zsrc_;
    const ZT* zdst = (const ZT*)zdst_;

    // W1^T packed in MFMA B-fragment order with the gather k-permutation:
    // slot (kb,nt), lane cl, 8 bf16: k0 = (kb>>2)*128 + ((kb>>1)&1)*64 + (cl>>4)*16 + (kb&1)*8
    __shared__ __bf16 sB[64 * 64 * 8];   // 64 KB

    const int tid  = threadIdx.x;
    const int lane = tid & 63;
    const int wave = tid >> 6;           // 0..3

    #pragma unroll
    for (int i = 0; i < 16; ++i) {
        int c    = tid + 256 * i;          // chunk 0..4095
        int cl   = c & 63;
        int slot = c >> 6;
        int kb   = slot >> 3, nt = slot & 7;
        int n    = nt * 16 + (cl & 15);
        int k0   = ((kb >> 2) << 7) + (((kb >> 1) & 1) << 6) + ((cl >> 4) << 4) + ((kb & 1) << 3);
        const float4* wp = reinterpret_cast<const float4*>(W1 + n * K2 + k0);
        float4 w0 = wp[0], w1 = wp[1];
        *reinterpret_cast<bf16x8*>(&sB[(size_t)c * 8]) = cvt8(w0, w1);
    }
    // per-lane epilogue constants
    float b1v[8], w2v[8];
    #pragma unroll
    for (int nt = 0; nt < 8; ++nt) {
        b1v[nt] = b1[nt * 16 + (lane & 15)];
        w2v[nt] = W2[nt * 16 + (lane & 15)];
    }
    const float bias2 = b2[0];
    __syncthreads();   // sB ready; no LDS writes after this -> no barriers in loop

    const int q = lane >> 4;   // lane quadrant 0..3

    for (int tile = blockIdx.x; tile < ntiles; tile += gridDim.x) {
        const int rbase = tile * BM + wave * 32;
        int e0 = rbase + (lane & 15);
        int e1 = e0 + 16;
        int e0c = e0 < E ? e0 : E - 1;
        int e1c = e1 < E ? e1 : E - 1;
        const ZT* a0s = zsrc + (size_t)row[e0c] * H;
        const ZT* a1s = zsrc + (size_t)row[e1c] * H;
        const ZT* a0d = zdst + (size_t)col[e0c] * H;
        const ZT* a1d = zdst + (size_t)col[e1c] * H;

        // A fragments for the 8 k-blocks of each edge-row (k-permuted layout).
        bf16x8 A0[8], A1[8];
        if constexpr (ZBF16) {
            // 32 B/lane loads; 4 sibling lanes (q=0..3) cover one 128-B segment.
            bf16x16 s00 = *reinterpret_cast<const bf16x16*>(a0s + (q << 4));
            bf16x16 s01 = *reinterpret_cast<const bf16x16*>(a0s + 64 + (q << 4));
            bf16x16 d00 = *reinterpret_cast<const bf16x16*>(a0d + (q << 4));
            bf16x16 d01 = *reinterpret_cast<const bf16x16*>(a0d + 64 + (q << 4));
            bf16x16 s10 = *reinterpret_cast<const bf16x16*>(a1s + (q << 4));
            bf16x16 s11 = *reinterpret_cast<const bf16x16*>(a1s + 64 + (q << 4));
            bf16x16 d10 = *reinterpret_cast<const bf16x16*>(a1d + (q << 4));
            bf16x16 d11 = *reinterpret_cast<const bf16x16*>(a1d + 64 + (q << 4));
            A0[0] = lo8(s00); A0[1] = hi8(s00); A0[2] = lo8(s01); A0[3] = hi8(s01);
            A0[4] = lo8(d00); A0[5] = hi8(d00); A0[6] = lo8(d01); A0[7] = hi8(d01);
            A1[0] = lo8(s10); A1[1] = hi8(s10); A1[2] = lo8(s11); A1[3] = hi8(s11);
            A1[4] = lo8(d10); A1[5] = hi8(d10); A1[6] = lo8(d11); A1[7] = hi8(d11);
        } else {
            #pragma unroll
            for (int kb = 0; kb < 8; ++kb) {
                const ZT* p0 = (kb < 4) ? a0s : a0d;
                const ZT* p1 = (kb < 4) ? a1s : a1d;
                const int ko = (((kb >> 1) & 1) << 6) + (q << 4) + ((kb & 1) << 3);
                const float4* q0 = reinterpret_cast<const float4*>((const float*)p0 + ko);
                const float4* q1 = reinterpret_cast<const float4*>((const float*)p1 + ko);
                A0[kb] = cvt8(q0[0], q0[1]);
                A1[kb] = cvt8(q1[0], q1[1]);
            }
        }

        f32x4 zero = {0.f, 0.f, 0.f, 0.f};
        f32x4 acc[2][8];
        #pragma unroll
        for (int mt = 0; mt < 2; ++mt)
            #pragma unroll
            for (int nt = 0; nt < 8; ++nt)
                acc[mt][nt] = zero;

        #pragma unroll
        for (int kb = 0; kb < 8; ++kb) {
            #pragma unroll
            for (int nt = 0; nt < 8; ++nt) {
                bf16x8 bfr = *reinterpret_cast<const bf16x8*>(&sB[(size_t)((kb * 8 + nt) * 64 + lane) * 8]);
                acc[0][nt] = __builtin_amdgcn_mfma_f32_16x16x32_bf16(A0[kb], bfr, acc[0][nt], 0, 0, 0);
                acc[1][nt] = __builtin_amdgcn_mfma_f32_16x16x32_bf16(A1[kb], bfr, acc[1][nt], 0, 0, 0);
            }
        }

        // epilogue: +b1, ReLU, dot W2 across n (in-wave), +b2, sigmoid, store
        #pragma unroll
        for (int mt = 0; mt < 2; ++mt) {
            #pragma unroll
            for (int r = 0; r < 4; ++r) {
                float p = 0.f;
                #pragma unroll
                for (int nt = 0; nt < 8; ++nt) {
                    float h = acc[mt][nt][r] + b1v[nt];
                    h = h > 0.f ? h : 0.f;
                    p += h * w2v[nt];
                }
                p += __shfl_xor(p, 1);
                p += __shfl_xor(p, 2);
                p += __shfl_xor(p, 4);
                p += __shfl_xor(p, 8);
                int e = rbase + mt * 16 + (q << 2) + r;
                if ((lane & 15) == 0 && e < E) {
                    float logit = p + bias2;
                    out[e] = 1.f / (1.f + __expf(-logit));
                }
            }
        }
    }
}

extern "C" void kernel_launch(void* const* d_in, const int* in_sizes, int n_in,
                              void* d_out, int out_size, void* d_ws, size_t ws_size,
                              hipStream_t stream) {
    const float* zsrc = (const float*)d_in[0];
    const float* zdst = (const float*)d_in[1];
    const int*   eli  = (const int*)d_in[2];   // [2,E] flat: row then col
    const float* W1   = (const float*)d_in[3];
    const float* b1   = (const float*)d_in[4];
    const float* W2   = (const float*)d_in[5];
    const float* b2   = (const float*)d_in[6];
    float* out = (float*)d_out;

    const int E = in_sizes[2] / 2;
    const int ntiles = (E + BM - 1) / BM;
    const int grid = ntiles < 1024 ? ntiles : 1024;

    const int nz = in_sizes[0] + in_sizes[1];
    const size_t need = (size_t)nz * sizeof(__bf16);
    if (ws_size >= need) {
        __bf16* zb = (__bf16*)d_ws;
        const int nchunks = nz / 8;
        prep_kernel<<<(nchunks + 255) / 256, 256, 0, stream>>>(zsrc, zdst, zb, in_sizes[0], nchunks);
        decoder_kernel<true><<<grid, 256, 0, stream>>>(zb, zb + in_sizes[0], eli, eli + E,
                                                       W1, b1, W2, b2, out, E, ntiles);
    } else {
        decoder_kernel<false><<<grid, 256, 0, stream>>>(zsrc, zdst, eli, eli + E,
                                                        W1, b1, W2, b2, out, E, ntiles);
    }
}

// Round 4
// 162.660 us; speedup vs baseline: 3.5637x; 1.8332x over previous
//
#include <hip/hip_runtime.h>
#include <hip/hip_bf16.h>

// Decoder_bipartite: out[e] = sigmoid( relu( [z_src[row[e]] ; z_dst[col[e]]] @ W1^T + b1 ) @ W2^T + b2 )
// R4: factor W1=[W1s|W1d]; precompute u_src=z_src@W1s^T, u_dst=z_dst@W1d^T (bf16, MFMA GEMM, fused cvt);
//     edge kernel = gather u_src[row]+u_dst[col], relu, dot W2 -> pure gather+VALU, no LDS cap.

#define H 128
#define K2 256

typedef __bf16 bf16x8 __attribute__((ext_vector_type(8)));
typedef float  f32x4  __attribute__((ext_vector_type(4)));

__device__ __forceinline__ bf16x8 cvt8(const float4 a, const float4 b) {
    bf16x8 r;
    r[0] = (__bf16)a.x; r[1] = (__bf16)a.y; r[2] = (__bf16)a.z; r[3] = (__bf16)a.w;
    r[4] = (__bf16)b.x; r[5] = (__bf16)b.y; r[6] = (__bf16)b.z; r[7] = (__bf16)b.w;
    return r;
}

// ---------------- prep: u = z @ W1half^T  (bf16 out, pair-permuted cols) ----------------
// u row storage (64 u32 words): word w = np*16+c holds cols j=(2np)*16+c (lo), (2np+1)*16+c (hi).
__global__ __launch_bounds__(256, 2)
void prep_gemm(const float* __restrict__ zsrc, const float* __restrict__ zdst,
               const float* __restrict__ W1,
               __bf16* __restrict__ usrc, __bf16* __restrict__ udst,
               int Msrc, int Mdst, int nsrc_tiles) {
    __shared__ __bf16 sB[32 * 64 * 8];   // 32 KB: [slot=kb*8+nt][lane][8]

    const int tid  = threadIdx.x;
    const int lane = tid & 63;
    const int wave = tid >> 6;
    const int q    = lane >> 4;

    const int  bt     = blockIdx.x;
    const bool is_src = bt < nsrc_tiles;
    const float* z    = is_src ? zsrc : zdst;
    __bf16*    u      = is_src ? usrc : udst;
    const int  M      = is_src ? Msrc : Mdst;
    const int  tile   = is_src ? bt : bt - nsrc_tiles;
    const int  hoff   = is_src ? 0 : H;

    // stage W1-half fragments: n = nt*16+(cl&15), k = kb*32+(cl>>4)*8 + [0..8)
    #pragma unroll
    for (int i = 0; i < 8; ++i) {
        int c    = tid + 256 * i;          // 0..2047
        int cl   = c & 63;
        int slot = c >> 6;                 // kb*8+nt
        int kb   = slot >> 3, nt = slot & 7;
        int n    = nt * 16 + (cl & 15);
        int k0   = kb * 32 + ((cl >> 4) << 3);
        const float4* wp = reinterpret_cast<const float4*>(W1 + (size_t)n * K2 + hoff + k0);
        *reinterpret_cast<bf16x8*>(&sB[(size_t)c * 8]) = cvt8(wp[0], wp[1]);
    }
    __syncthreads();

    const int rbase = tile * 128 + wave * 32;
    int m0 = rbase + (lane & 15);
    int m1 = m0 + 16;
    int m0c = m0 < M ? m0 : M - 1;
    int m1c = m1 < M ? m1 : M - 1;
    const float* a0 = z + (size_t)m0c * H;
    const float* a1 = z + (size_t)m1c * H;

    bf16x8 A0[4], A1[4];
    #pragma unroll
    for (int kb = 0; kb < 4; ++kb) {
        const float4* q0 = reinterpret_cast<const float4*>(a0 + kb * 32 + q * 8);
        const float4* q1 = reinterpret_cast<const float4*>(a1 + kb * 32 + q * 8);
        A0[kb] = cvt8(q0[0], q0[1]);
        A1[kb] = cvt8(q1[0], q1[1]);
    }

    f32x4 zero = {0.f, 0.f, 0.f, 0.f};
    f32x4 acc[2][8];
    #pragma unroll
    for (int mt = 0; mt < 2; ++mt)
        #pragma unroll
        for (int nt = 0; nt < 8; ++nt) acc[mt][nt] = zero;

    #pragma unroll
    for (int kb = 0; kb < 4; ++kb)
        #pragma unroll
        for (int nt = 0; nt < 8; ++nt) {
            bf16x8 bfr = *reinterpret_cast<const bf16x8*>(&sB[(size_t)((kb * 8 + nt) * 64 + lane) * 8]);
            acc[0][nt] = __builtin_amdgcn_mfma_f32_16x16x32_bf16(A0[kb], bfr, acc[0][nt], 0, 0, 0);
            acc[1][nt] = __builtin_amdgcn_mfma_f32_16x16x32_bf16(A1[kb], bfr, acc[1][nt], 0, 0, 0);
        }

    // store: C row = rbase+mt*16+q*4+r, packed col-pairs -> coalesced u32 stores
    #pragma unroll
    for (int mt = 0; mt < 2; ++mt)
        #pragma unroll
        for (int r = 0; r < 4; ++r) {
            int rowo = rbase + mt * 16 + q * 4 + r;
            if (rowo < M) {
                unsigned* urow = reinterpret_cast<unsigned*>(u + (size_t)rowo * H);
                #pragma unroll
                for (int np = 0; np < 4; ++np) {
                    union { __bf16 h[2]; unsigned w; } pk;
                    pk.h[0] = (__bf16)acc[mt][2 * np][r];
                    pk.h[1] = (__bf16)acc[mt][2 * np + 1][r];
                    urow[np * 16 + (lane & 15)] = pk.w;
                }
            }
        }
}

// ---------------- edge kernel: gather + relu + dot ----------------
__global__ __launch_bounds__(256, 4)
void edge_kernel(const __bf16* __restrict__ usrc, const __bf16* __restrict__ udst,
                 const int* __restrict__ row, const int* __restrict__ col,
                 const float* __restrict__ b1, const float* __restrict__ W2,
                 const float* __restrict__ b2, float* __restrict__ out, int E) {
    // b1/W2 staged in the u-permutation: storage elem s -> j = (2*(s>>5)+(s&1))*16 + ((s>>1)&15)
    __shared__ float4 sbw4[64];   // [w] = {b1[j(2w)], W2[j(2w)], b1[j(2w+1)], W2[j(2w+1)]}
    const int tid = threadIdx.x;
    if (tid < 64) {
        int s0 = 2 * tid, s1 = s0 + 1;
        int j0 = ((s0 >> 5) * 2 + (s0 & 1)) * 16 + ((s0 >> 1) & 15);
        int j1 = ((s1 >> 5) * 2 + (s1 & 1)) * 16 + ((s1 >> 1) & 15);
        sbw4[tid] = make_float4(b1[j0], W2[j0], b1[j1], W2[j1]);
    }
    __syncthreads();

    int e = blockIdx.x * blockDim.x + tid;
    if (e >= E) return;

    const bf16x8* ps = reinterpret_cast<const bf16x8*>(usrc + (size_t)row[e] * H);
    const bf16x8* pd = reinterpret_cast<const bf16x8*>(udst + (size_t)col[e] * H);

    float logit = b2[0];
    #pragma unroll
    for (int ch = 0; ch < 2; ++ch) {
        bf16x8 a[8], b[8];
        #pragma unroll
        for (int t = 0; t < 8; ++t) { a[t] = ps[ch * 8 + t]; b[t] = pd[ch * 8 + t]; }
        #pragma unroll
        for (int t = 0; t < 8; ++t) {
            const int f4 = (ch * 8 + t) * 4;
            #pragma unroll
            for (int ii = 0; ii < 4; ++ii) {
                float4 v = sbw4[f4 + ii];
                float h0 = fmaxf((float)a[t][2 * ii]     + (float)b[t][2 * ii]     + v.x, 0.f);
                logit = fmaf(h0, v.y, logit);
                float h1 = fmaxf((float)a[t][2 * ii + 1] + (float)b[t][2 * ii + 1] + v.z, 0.f);
                logit = fmaf(h1, v.w, logit);
            }
        }
    }
    out[e] = 1.f / (1.f + __expf(-logit));
}

// ---------------- fallback (ws too small): direct f32 MFMA kernel (R3 structure) ----------------
__global__ __launch_bounds__(256, 2)
void decoder_f32(const float* __restrict__ zsrc, const float* __restrict__ zdst,
                 const int* __restrict__ row, const int* __restrict__ col,
                 const float* __restrict__ W1, const float* __restrict__ b1,
                 const float* __restrict__ W2, const float* __restrict__ b2,
                 float* __restrict__ out, int E, int ntiles) {
    __shared__ __bf16 sB[64 * 64 * 8];
    const int tid = threadIdx.x, lane = tid & 63, wave = tid >> 6, q = lane >> 4;
    #pragma unroll
    for (int i = 0; i < 16; ++i) {
        int c = tid + 256 * i, cl = c & 63, slot = c >> 6;
        int kb = slot >> 3, nt = slot & 7;
        int n = nt * 16 + (cl & 15);
        int k0 = kb * 32 + ((cl >> 4) << 3);
        const float4* wp = reinterpret_cast<const float4*>(W1 + (size_t)n * K2 + k0);
        *reinterpret_cast<bf16x8*>(&sB[(size_t)c * 8]) = cvt8(wp[0], wp[1]);
    }
    float b1v[8], w2v[8];
    #pragma unroll
    for (int nt = 0; nt < 8; ++nt) { b1v[nt] = b1[nt * 16 + (lane & 15)]; w2v[nt] = W2[nt * 16 + (lane & 15)]; }
    const float bias2 = b2[0];
    __syncthreads();
    for (int tile = blockIdx.x; tile < ntiles; tile += gridDim.x) {
        const int rbase = tile * 128 + wave * 32;
        int e0 = rbase + (lane & 15), e1 = e0 + 16;
        int e0c = e0 < E ? e0 : E - 1, e1c = e1 < E ? e1 : E - 1;
        const float* a0s = zsrc + (size_t)row[e0c] * H;
        const float* a1s = zsrc + (size_t)row[e1c] * H;
        const float* a0d = zdst + (size_t)col[e0c] * H;
        const float* a1d = zdst + (size_t)col[e1c] * H;
        f32x4 zero = {0.f, 0.f, 0.f, 0.f};
        f32x4 acc[2][8];
        #pragma unroll
        for (int mt = 0; mt < 2; ++mt)
            #pragma unroll
            for (int nt = 0; nt < 8; ++nt) acc[mt][nt] = zero;
        #pragma unroll
        for (int kb = 0; kb < 8; ++kb) {
            const float* p0 = (kb < 4) ? a0s : a0d;
            const float* p1 = (kb < 4) ? a1s : a1d;
            const int ko = ((kb & 3) << 5) + (q << 3);
            const float4* q0 = reinterpret_cast<const float4*>(p0 + ko);
            const float4* q1 = reinterpret_cast<const float4*>(p1 + ko);
            bf16x8 afr0 = cvt8(q0[0], q0[1]);
            bf16x8 afr1 = cvt8(q1[0], q1[1]);
            #pragma unroll
            for (int nt = 0; nt < 8; ++nt) {
                bf16x8 bfr = *reinterpret_cast<const bf16x8*>(&sB[(size_t)((kb * 8 + nt) * 64 + lane) * 8]);
                acc[0][nt] = __builtin_amdgcn_mfma_f32_16x16x32_bf16(afr0, bfr, acc[0][nt], 0, 0, 0);
                acc[1][nt] = __builtin_amdgcn_mfma_f32_16x16x32_bf16(afr1, bfr, acc[1][nt], 0, 0, 0);
            }
        }
        #pragma unroll
        for (int mt = 0; mt < 2; ++mt)
            #pragma unroll
            for (int r = 0; r < 4; ++r) {
                float p = 0.f;
                #pragma unroll
                for (int nt = 0; nt < 8; ++nt) {
                    float h = acc[mt][nt][r] + b1v[nt];
                    h = h > 0.f ? h : 0.f;
                    p += h * w2v[nt];
                }
                p += __shfl_xor(p, 1); p += __shfl_xor(p, 2);
                p += __shfl_xor(p, 4); p += __shfl_xor(p, 8);
                int e = rbase + mt * 16 + (q << 2) + r;
                if ((lane & 15) == 0 && e < E)
                    out[e] = 1.f / (1.f + __expf(-(p + bias2)));
            }
    }
}

extern "C" void kernel_launch(void* const* d_in, const int* in_sizes, int n_in,
                              void* d_out, int out_size, void* d_ws, size_t ws_size,
                              hipStream_t stream) {
    const float* zsrc = (const float*)d_in[0];
    const float* zdst = (const float*)d_in[1];
    const int*   eli  = (const int*)d_in[2];   // [2,E] flat: row then col
    const float* W1   = (const float*)d_in[3];
    const float* b1   = (const float*)d_in[4];
    const float* W2   = (const float*)d_in[5];
    const float* b2   = (const float*)d_in[6];
    float* out = (float*)d_out;

    const int E    = in_sizes[2] / 2;
    const int Msrc = in_sizes[0] / H;
    const int Mdst = in_sizes[1] / H;

    const size_t need = ((size_t)Msrc + Mdst) * H * sizeof(__bf16);
    if (ws_size >= need) {
        __bf16* usrc = (__bf16*)d_ws;
        __bf16* udst = usrc + (size_t)Msrc * H;
        const int nsrc_tiles = (Msrc + 127) / 128;
        const int ndst_tiles = (Mdst + 127) / 128;
        prep_gemm<<<nsrc_tiles + ndst_tiles, 256, 0, stream>>>(zsrc, zdst, W1, usrc, udst,
                                                               Msrc, Mdst, nsrc_tiles);
        edge_kernel<<<(E + 255) / 256, 256, 0, stream>>>(usrc, udst, eli, eli + E,
                                                         b1, W2, b2, out, E);
    } else {
        const int ntiles = (E + 127) / 128;
        const int grid = ntiles < 1024 ? ntiles : 1024;
        decoder_f32<<<grid, 256, 0, stream>>>(zsrc, zdst, eli, eli + E,
                                              W1, b1, W2, b2, out, E, ntiles);
    }
}

// Round 5
// 94.498 us; speedup vs baseline: 6.1342x; 1.7213x over previous
//
#include <hip/hip_runtime.h>
#include <hip/hip_bf16.h>

// Decoder_bipartite: out[e] = sigmoid( relu( [z_src[row[e]] ; z_dst[col[e]]] @ W1^T + b1 ) @ W2^T + b2 )
// R5: quad-per-edge gather (8 independent 16B loads/lane, hoisted -> deep MLP) on top of R4's
//     factorization: u_src=z_src@W1s^T, u_dst=z_dst@W1d^T precomputed in bf16 (pair-permuted rows).

#define H 128
#define K2 256

typedef __bf16 bf16x8 __attribute__((ext_vector_type(8)));
typedef float  f32x4  __attribute__((ext_vector_type(4)));

__device__ __forceinline__ bf16x8 cvt8(const float4 a, const float4 b) {
    bf16x8 r;
    r[0] = (__bf16)a.x; r[1] = (__bf16)a.y; r[2] = (__bf16)a.z; r[3] = (__bf16)a.w;
    r[4] = (__bf16)b.x; r[5] = (__bf16)b.y; r[6] = (__bf16)b.z; r[7] = (__bf16)b.w;
    return r;
}

// ---------------- prep: u = z @ W1half^T  (bf16 out, pair-permuted cols) ----------------
// u row storage (64 u32 words): word w = np*16+c holds cols j=(2np)*16+c (lo), (2np+1)*16+c (hi).
__global__ __launch_bounds__(256, 2)
void prep_gemm(const float* __restrict__ zsrc, const float* __restrict__ zdst,
               const float* __restrict__ W1,
               __bf16* __restrict__ usrc, __bf16* __restrict__ udst,
               int Msrc, int Mdst, int nsrc_tiles) {
    __shared__ __bf16 sB[32 * 64 * 8];   // 32 KB: [slot=kb*8+nt][lane][8]

    const int tid  = threadIdx.x;
    const int lane = tid & 63;
    const int wave = tid >> 6;
    const int q    = lane >> 4;

    const int  bt     = blockIdx.x;
    const bool is_src = bt < nsrc_tiles;
    const float* z    = is_src ? zsrc : zdst;
    __bf16*    u      = is_src ? usrc : udst;
    const int  M      = is_src ? Msrc : Mdst;
    const int  tile   = is_src ? bt : bt - nsrc_tiles;
    const int  hoff   = is_src ? 0 : H;

    #pragma unroll
    for (int i = 0; i < 8; ++i) {
        int c    = tid + 256 * i;          // 0..2047
        int cl   = c & 63;
        int slot = c >> 6;                 // kb*8+nt
        int kb   = slot >> 3, nt = slot & 7;
        int n    = nt * 16 + (cl & 15);
        int k0   = kb * 32 + ((cl >> 4) << 3);
        const float4* wp = reinterpret_cast<const float4*>(W1 + (size_t)n * K2 + hoff + k0);
        *reinterpret_cast<bf16x8*>(&sB[(size_t)c * 8]) = cvt8(wp[0], wp[1]);
    }
    __syncthreads();

    const int rbase = tile * 128 + wave * 32;
    int m0 = rbase + (lane & 15);
    int m1 = m0 + 16;
    int m0c = m0 < M ? m0 : M - 1;
    int m1c = m1 < M ? m1 : M - 1;
    const float* a0 = z + (size_t)m0c * H;
    const float* a1 = z + (size_t)m1c * H;

    bf16x8 A0[4], A1[4];
    #pragma unroll
    for (int kb = 0; kb < 4; ++kb) {
        const float4* q0 = reinterpret_cast<const float4*>(a0 + kb * 32 + q * 8);
        const float4* q1 = reinterpret_cast<const float4*>(a1 + kb * 32 + q * 8);
        A0[kb] = cvt8(q0[0], q0[1]);
        A1[kb] = cvt8(q1[0], q1[1]);
    }

    f32x4 zero = {0.f, 0.f, 0.f, 0.f};
    f32x4 acc[2][8];
    #pragma unroll
    for (int mt = 0; mt < 2; ++mt)
        #pragma unroll
        for (int nt = 0; nt < 8; ++nt) acc[mt][nt] = zero;

    #pragma unroll
    for (int kb = 0; kb < 4; ++kb)
        #pragma unroll
        for (int nt = 0; nt < 8; ++nt) {
            bf16x8 bfr = *reinterpret_cast<const bf16x8*>(&sB[(size_t)((kb * 8 + nt) * 64 + lane) * 8]);
            acc[0][nt] = __builtin_amdgcn_mfma_f32_16x16x32_bf16(A0[kb], bfr, acc[0][nt], 0, 0, 0);
            acc[1][nt] = __builtin_amdgcn_mfma_f32_16x16x32_bf16(A1[kb], bfr, acc[1][nt], 0, 0, 0);
        }

    #pragma unroll
    for (int mt = 0; mt < 2; ++mt)
        #pragma unroll
        for (int r = 0; r < 4; ++r) {
            int rowo = rbase + mt * 16 + q * 4 + r;
            if (rowo < M) {
                unsigned* urow = reinterpret_cast<unsigned*>(u + (size_t)rowo * H);
                #pragma unroll
                for (int np = 0; np < 4; ++np) {
                    union { __bf16 h[2]; unsigned w; } pk;
                    pk.h[0] = (__bf16)acc[mt][2 * np][r];
                    pk.h[1] = (__bf16)acc[mt][2 * np + 1][r];
                    urow[np * 16 + (lane & 15)] = pk.w;
                }
            }
        }
}

// ---------------- edge kernel: quad-per-edge gather + relu + dot ----------------
__global__ __launch_bounds__(256, 4)
void edge_kernel(const __bf16* __restrict__ usrc, const __bf16* __restrict__ udst,
                 const int* __restrict__ row, const int* __restrict__ col,
                 const float* __restrict__ b1, const float* __restrict__ W2,
                 const float* __restrict__ b2, float* __restrict__ out, int E) {
    // b1/W2 staged in the u-permutation: word w -> j0=2*(w>>4)*16+(w&15), j1=(2*(w>>4)+1)*16+(w&15)
    __shared__ float4 sbw4[64];   // [w] = {b1[j0], W2[j0], b1[j1], W2[j1]}
    const int tid = threadIdx.x;
    if (tid < 64) {
        int np = tid >> 4, c = tid & 15;
        int j0 = (2 * np) * 16 + c;
        int j1 = (2 * np + 1) * 16 + c;
        sbw4[tid] = make_float4(b1[j0], W2[j0], b1[j1], W2[j1]);
    }
    __syncthreads();

    const int q = tid & 3;                      // lane-in-quad
    const int e = blockIdx.x * 64 + (tid >> 2); // 64 edges per 256-thr block
    if (e >= E) return;                         // uniform within a quad

    const char* ps = reinterpret_cast<const char*>(usrc + (size_t)row[e] * H) + q * 64;
    const char* pd = reinterpret_cast<const char*>(udst + (size_t)col[e] * H) + q * 64;

    // 8 independent 16-B loads -> all in flight before first use
    bf16x8 a[4], b[4];
    #pragma unroll
    for (int t = 0; t < 4; ++t) a[t] = *reinterpret_cast<const bf16x8*>(ps + t * 16);
    #pragma unroll
    for (int t = 0; t < 4; ++t) b[t] = *reinterpret_cast<const bf16x8*>(pd + t * 16);

    float acc = 0.f;
    #pragma unroll
    for (int t = 0; t < 4; ++t) {
        const int wbase = q * 16 + t * 4;
        #pragma unroll
        for (int d = 0; d < 4; ++d) {
            float4 v = sbw4[wbase + d];
            float h0 = fmaxf((float)a[t][2 * d]     + (float)b[t][2 * d]     + v.x, 0.f);
            acc = fmaf(h0, v.y, acc);
            float h1 = fmaxf((float)a[t][2 * d + 1] + (float)b[t][2 * d + 1] + v.z, 0.f);
            acc = fmaf(h1, v.w, acc);
        }
    }
    acc += __shfl_xor(acc, 1);
    acc += __shfl_xor(acc, 2);
    if (q == 0)
        out[e] = 1.f / (1.f + __expf(-(acc + b2[0])));
}

// ---------------- fallback (ws too small): direct MFMA kernel (R3 structure) ----------------
__global__ __launch_bounds__(256, 2)
void decoder_f32(const float* __restrict__ zsrc, const float* __restrict__ zdst,
                 const int* __restrict__ row, const int* __restrict__ col,
                 const float* __restrict__ W1, const float* __restrict__ b1,
                 const float* __restrict__ W2, const float* __restrict__ b2,
                 float* __restrict__ out, int E, int ntiles) {
    __shared__ __bf16 sB[64 * 64 * 8];
    const int tid = threadIdx.x, lane = tid & 63, wave = tid >> 6, q = lane >> 4;
    #pragma unroll
    for (int i = 0; i < 16; ++i) {
        int c = tid + 256 * i, cl = c & 63, slot = c >> 6;
        int kb = slot >> 3, nt = slot & 7;
        int n = nt * 16 + (cl & 15);
        int k0 = kb * 32 + ((cl >> 4) << 3);
        const float4* wp = reinterpret_cast<const float4*>(W1 + (size_t)n * K2 + k0);
        *reinterpret_cast<bf16x8*>(&sB[(size_t)c * 8]) = cvt8(wp[0], wp[1]);
    }
    float b1v[8], w2v[8];
    #pragma unroll
    for (int nt = 0; nt < 8; ++nt) { b1v[nt] = b1[nt * 16 + (lane & 15)]; w2v[nt] = W2[nt * 16 + (lane & 15)]; }
    const float bias2 = b2[0];
    __syncthreads();
    for (int tile = blockIdx.x; tile < ntiles; tile += gridDim.x) {
        const int rbase = tile * 128 + wave * 32;
        int e0 = rbase + (lane & 15), e1 = e0 + 16;
        int e0c = e0 < E ? e0 : E - 1, e1c = e1 < E ? e1 : E - 1;
        const float* a0s = zsrc + (size_t)row[e0c] * H;
        const float* a1s = zsrc + (size_t)row[e1c] * H;
        const float* a0d = zdst + (size_t)col[e0c] * H;
        const float* a1d = zdst + (size_t)col[e1c] * H;
        f32x4 zero = {0.f, 0.f, 0.f, 0.f};
        f32x4 acc[2][8];
        #pragma unroll
        for (int mt = 0; mt < 2; ++mt)
            #pragma unroll
            for (int nt = 0; nt < 8; ++nt) acc[mt][nt] = zero;
        #pragma unroll
        for (int kb = 0; kb < 8; ++kb) {
            const float* p0 = (kb < 4) ? a0s : a0d;
            const float* p1 = (kb < 4) ? a1s : a1d;
            const int ko = ((kb & 3) << 5) + (q << 3);
            const float4* q0 = reinterpret_cast<const float4*>(p0 + ko);
            const float4* q1 = reinterpret_cast<const float4*>(p1 + ko);
            bf16x8 afr0 = cvt8(q0[0], q0[1]);
            bf16x8 afr1 = cvt8(q1[0], q1[1]);
            #pragma unroll
            for (int nt = 0; nt < 8; ++nt) {
                bf16x8 bfr = *reinterpret_cast<const bf16x8*>(&sB[(size_t)((kb * 8 + nt) * 64 + lane) * 8]);
                acc[0][nt] = __builtin_amdgcn_mfma_f32_16x16x32_bf16(afr0, bfr, acc[0][nt], 0, 0, 0);
                acc[1][nt] = __builtin_amdgcn_mfma_f32_16x16x32_bf16(afr1, bfr, acc[1][nt], 0, 0, 0);
            }
        }
        #pragma unroll
        for (int mt = 0; mt < 2; ++mt)
            #pragma unroll
            for (int r = 0; r < 4; ++r) {
                float p = 0.f;
                #pragma unroll
                for (int nt = 0; nt < 8; ++nt) {
                    float h = acc[mt][nt][r] + b1v[nt];
                    h = h > 0.f ? h : 0.f;
                    p += h * w2v[nt];
                }
                p += __shfl_xor(p, 1); p += __shfl_xor(p, 2);
                p += __shfl_xor(p, 4); p += __shfl_xor(p, 8);
                int e = rbase + mt * 16 + (q << 2) + r;
                if ((lane & 15) == 0 && e < E)
                    out[e] = 1.f / (1.f + __expf(-(p + bias2)));
            }
    }
}

extern "C" void kernel_launch(void* const* d_in, const int* in_sizes, int n_in,
                              void* d_out, int out_size, void* d_ws, size_t ws_size,
                              hipStream_t stream) {
    const float* zsrc = (const float*)d_in[0];
    const float* zdst = (const float*)d_in[1];
    const int*   eli  = (const int*)d_in[2];   // [2,E] flat: row then col
    const float* W1   = (const float*)d_in[3];
    const float* b1   = (const float*)d_in[4];
    const float* W2   = (const float*)d_in[5];
    const float* b2   = (const float*)d_in[6];
    float* out = (float*)d_out;

    const int E    = in_sizes[2] / 2;
    const int Msrc = in_sizes[0] / H;
    const int Mdst = in_sizes[1] / H;

    const size_t need = ((size_t)Msrc + Mdst) * H * sizeof(__bf16);
    if (ws_size >= need) {
        __bf16* usrc = (__bf16*)d_ws;
        __bf16* udst = usrc + (size_t)Msrc * H;
        const int nsrc_tiles = (Msrc + 127) / 128;
        const int ndst_tiles = (Mdst + 127) / 128;
        prep_gemm<<<nsrc_tiles + ndst_tiles, 256, 0, stream>>>(zsrc, zdst, W1, usrc, udst,
                                                               Msrc, Mdst, nsrc_tiles);
        edge_kernel<<<(E + 63) / 64, 256, 0, stream>>>(usrc, udst, eli, eli + E,
                                                       b1, W2, b2, out, E);
    } else {
        const int ntiles = (E + 127) / 128;
        const int grid = ntiles < 1024 ? ntiles : 1024;
        decoder_f32<<<grid, 256, 0, stream>>>(zsrc, zdst, eli, eli + E,
                                              W1, b1, W2, b2, out, E, ntiles);
    }
}